// Round 9
// baseline (21.601 us; speedup 1.0000x reference)
//
#include <hip/hip_runtime.h>

// MarginRankingLoss over all B*B pairs.
// loss[m,n] = max(0, BIAS - 0.5*(w_m+w_n)*|p_m-p_n|)  (exact per-pair rewrite:
// the gt tie-break only affects r when diff==0, where r*diff==0 anyway).
//
// R9: single-kernel structure. R4 showed per-wave __threadfence is catastrophic
// (~25ns L2 flush each); R8 showed triangle/irregular structures lose to the
// flat loop. Here the cross-block combine uses ONE u64 atomicAdd per block with
// count packed in bits [48:63] and a 2^-22 fixed-point sum in bits [0:47] —
// same-address atomic total ordering replaces any fence. The block that
// receives old_count == nBlocks-1 holds the full sum and writes out[0].
// Deterministic: fixed-point addition is order-independent. A 16-byte memset
// node zeroes the accumulator every replay (d_ws is not re-poisoned).
// Inner loop = R6 packed fp32 + med3: t1=BIAS-w*d, t2=BIAS+w*d, t1+t2>0 =>
// max(0,min(t1,t2)) == v_med3_f32(t1,t2,0) exactly.

#define BIAS_F 0.1f
#define FIX_SCALE 4194304.0   // 2^22

typedef float v2f __attribute__((ext_vector_type(2)));

constexpr int TPB = 1024;      // threads per block (16 waves)
constexpr int NPT = 8;         // n-values per thread
constexpr int NG  = NPT / 2;   // float2 groups
constexpr int TNF = TPB * NPT; // 8192 n per block-pass
constexpr int TM  = 32;        // m rows per block

__global__ __launch_bounds__(TPB) void pair_loss_kernel(
    const float* __restrict__ pred,
    const float* __restrict__ weight,
    unsigned long long* __restrict__ acc, // d_ws, zeroed by memset node
    float* __restrict__ out,
    int B, int nBlocks)
{
    const int m_base = blockIdx.x * TM;
    const int t = threadIdx.x;

    float s_thread = 0.0f;
    const v2f BIAS2 = (v2f){BIAS_F, BIAS_F};

    // Outer n-chunk loop (single pass at B=8192).
    for (int n_base = 0; n_base < B; n_base += TNF) {
        v2f pn2[NG], wn2[NG], mask2[NG];
        const int n_first = n_base + 8 * t;

        if (n_base + TNF <= B) {
            const float4* p4 = reinterpret_cast<const float4*>(pred   + n_base) + 2 * t;
            const float4* w4 = reinterpret_cast<const float4*>(weight + n_base) + 2 * t;
            float4 pa = p4[0], pb = p4[1];
            float4 wa = w4[0], wb = w4[1];
            pn2[0] = (v2f){pa.x, pa.y}; pn2[1] = (v2f){pa.z, pa.w};
            pn2[2] = (v2f){pb.x, pb.y}; pn2[3] = (v2f){pb.z, pb.w};
            wn2[0] = (v2f){wa.x, wa.y} * 0.5f; wn2[1] = (v2f){wa.z, wa.w} * 0.5f;
            wn2[2] = (v2f){wb.x, wb.y} * 0.5f; wn2[3] = (v2f){wb.z, wb.w} * 0.5f;
            #pragma unroll
            for (int j = 0; j < NG; ++j) mask2[j] = (v2f){1.0f, 1.0f};
        } else {
            #pragma unroll
            for (int j = 0; j < NG; ++j) {
                #pragma unroll
                for (int e = 0; e < 2; ++e) {
                    int n = n_first + 2 * j + e;
                    bool ok = (n < B);
                    int nc = ok ? n : 0;
                    pn2[j][e]   = pred[nc];
                    wn2[j][e]   = weight[nc] * 0.5f;
                    mask2[j][e] = ok ? 1.0f : 0.0f;
                }
            }
        }

        v2f acc2[NG];
        #pragma unroll
        for (int j = 0; j < NG; ++j) acc2[j] = (v2f){0.0f, 0.0f};

        const int m_end = (m_base + TM <= B) ? TM : (B - m_base);
        #pragma unroll 4
        for (int i = 0; i < m_end; ++i) {
            const int m = m_base + i;
            const float pm  = pred[m];          // uniform -> scalar load
            const float wmh = weight[m] * 0.5f;
            const v2f pm2 = (v2f){pm, pm};
            const v2f wm2 = (v2f){wmh, wmh};
            #pragma unroll
            for (int j = 0; j < NG; ++j) {
                v2f d  = pm2 - pn2[j];                             // v_pk_add
                v2f w  = wm2 + wn2[j];                             // v_pk_add
                v2f t1 = __builtin_elementwise_fma(-w, d, BIAS2);  // v_pk_fma
                v2f t2 = __builtin_elementwise_fma( w, d, BIAS2);  // v_pk_fma
                v2f h;
                h.x = __builtin_amdgcn_fmed3f(t1.x, t2.x, 0.0f);   // v_med3
                h.y = __builtin_amdgcn_fmed3f(t1.y, t2.y, 0.0f);
                acc2[j] += h;                                      // v_pk_add
            }
        }

        #pragma unroll
        for (int j = 0; j < NG; ++j)
            s_thread += mask2[j].x * acc2[j].x + mask2[j].y * acc2[j].y;
    }

    // wave (64-lane) reduction
    float s = s_thread;
    #pragma unroll
    for (int off = 32; off > 0; off >>= 1)
        s += __shfl_down(s, off, 64);

    __shared__ float lds[TPB / 64];
    const int lane = t & 63, wid = t >> 6;
    if (lane == 0) lds[wid] = s;
    __syncthreads();

    if (t == 0) {
        float bs = 0.0f;
        #pragma unroll
        for (int w = 0; w < TPB / 64; ++w) bs += lds[w];
        // Fixed-point block contribution (exact, order-independent).
        unsigned long long fix =
            (unsigned long long)llrint((double)bs * FIX_SCALE);
        unsigned long long add = (1ULL << 48) | fix;
        unsigned long long old = atomicAdd(acc, add);
        if ((old >> 48) == (unsigned long long)(nBlocks - 1)) {
            // All other blocks' contributions are in `old` (same-address
            // atomic total order); no fence needed.
            unsigned long long total_fix = (old & ((1ULL << 48) - 1)) + fix;
            double total = (double)total_fix / FIX_SCALE;
            out[0] = (float)(total / ((double)B * (double)B));
        }
    }
}

extern "C" void kernel_launch(void* const* d_in, const int* in_sizes, int n_in,
                              void* d_out, int out_size, void* d_ws, size_t ws_size,
                              hipStream_t stream) {
    const float* pred   = (const float*)d_in[0];
    // d_in[1] = correct_output — mathematically irrelevant (see header comment)
    const float* weight = (const float*)d_in[2];
    float* out = (float*)d_out;
    const int B = in_sizes[0];

    unsigned long long* acc = (unsigned long long*)d_ws;
    // Zero the packed accumulator every call (graph node; ws not re-poisoned).
    hipMemsetAsync(acc, 0, 8, stream);

    const int nBlocks = (B + TM - 1) / TM;   // 256 at B=8192 (1 per CU)
    pair_loss_kernel<<<nBlocks, TPB, 0, stream>>>(pred, weight, acc, out, B, nBlocks);
}